// Round 3
// baseline (787.563 us; speedup 1.0000x reference)
//
#include <hip/hip_runtime.h>

#define NN   50000
#define EE   800000
#define INC  128
#define OUTC 256
#define HALF 128
#define NREL 6
#define NCELL (NN * NREL)   // 300000

typedef __attribute__((ext_vector_type(4))) short s16x4;
typedef __attribute__((ext_vector_type(8))) short bf16x8;
typedef __attribute__((ext_vector_type(4))) float f32x4;

__device__ __forceinline__ float b2f(short b) {
    unsigned u = ((unsigned)(unsigned short)b) << 16;
    return __uint_as_float(u);
}
__device__ __forceinline__ short f2b(float f) {
    unsigned u = __float_as_uint(f);
    unsigned r = (u + 0x7fffu + ((u >> 16) & 1u)) >> 16;   // RNE
    return (short)r;
}

__device__ __forceinline__ void gload16(const void* g, void* l) {
    __builtin_amdgcn_global_load_lds(
        (const __attribute__((address_space(1))) void*)g,
        (__attribute__((address_space(3))) void*)l, 16, 0, 0);
}

// ---------------- CSR build ----------------
__global__ __launch_bounds__(256) void count_k(const int* __restrict__ dst,
                                               const int* __restrict__ et,
                                               int* __restrict__ cnt) {
    int e = blockIdx.x * 256 + threadIdx.x;
    if (e < EE) atomicAdd(&cnt[dst[e] * NREL + et[e]], 1);
}

__global__ __launch_bounds__(256) void scanA_k(const int* __restrict__ cnt,
                                               int* __restrict__ off,
                                               int* __restrict__ bsum, int n) {
    __shared__ int sh[256];
    int t = threadIdx.x;
    int base = blockIdx.x * 512 + t * 2;
    int v0 = (base < n) ? cnt[base] : 0;
    int v1 = (base + 1 < n) ? cnt[base + 1] : 0;
    int s = v0 + v1;
    sh[t] = s; __syncthreads();
    for (int o = 1; o < 256; o <<= 1) {
        int u = (t >= o) ? sh[t - o] : 0;
        __syncthreads();
        sh[t] += u;
        __syncthreads();
    }
    int excl = sh[t] - s;
    if (base < n)     off[base]     = excl;
    if (base + 1 < n) off[base + 1] = excl + v0;
    if (t == 255) bsum[blockIdx.x] = sh[255];
}

__global__ __launch_bounds__(1024) void scanB_k(int* __restrict__ bsum, int nb) {
    __shared__ int sh[1024];
    int t = threadIdx.x;
    int s = (t < nb) ? bsum[t] : 0;
    sh[t] = s; __syncthreads();
    for (int o = 1; o < 1024; o <<= 1) {
        int u = (t >= o) ? sh[t - o] : 0;
        __syncthreads();
        sh[t] += u;
        __syncthreads();
    }
    if (t < nb) bsum[t] = sh[t] - s;
}

__global__ __launch_bounds__(256) void scanC_k(int* __restrict__ off,
                                               const int* __restrict__ bsum, int n) {
    int i = blockIdx.x * 256 + threadIdx.x;
    if (i < n) off[i] += bsum[i >> 9];
    if (i == 0) off[n] = EE;
}

__global__ __launch_bounds__(256) void copyint_k(const int* __restrict__ a,
                                                 int* __restrict__ b, int n) {
    int i = blockIdx.x * 256 + threadIdx.x;
    if (i < n) b[i] = a[i];
}

__global__ __launch_bounds__(256) void fill_k(const int* __restrict__ src,
                                              const int* __restrict__ dst,
                                              const int* __restrict__ et,
                                              int* __restrict__ cur,
                                              int* __restrict__ es) {
    int e = blockIdx.x * 256 + threadIdx.x;
    if (e < EE) {
        int key = dst[e] * NREL + et[e];
        int p = atomicAdd(&cur[key], 1);
        es[p] = src[e];
    }
}

// ---------------- casts ----------------
__global__ __launch_bounds__(256) void cast_x_k(const float* __restrict__ x,
                                                short* __restrict__ xb, int n4) {
    int i = blockIdx.x * 256 + threadIdx.x;
    if (i < n4) {
        float4 v = ((const float4*)x)[i];
        s16x4 o;
        o[0] = f2b(v.x); o[1] = f2b(v.y); o[2] = f2b(v.z); o[3] = f2b(v.w);
        ((s16x4*)xb)[i] = o;
    }
}

// WT[Ncols][Ktot] = [root; W]^T  (bf16)
__global__ __launch_bounds__(256) void wtcat_k(const float* __restrict__ root,
                                               const float* __restrict__ W,
                                               int K0, int Ktot, int Ncols,
                                               short* __restrict__ WT) {
    int i = blockIdx.x * 256 + threadIdx.x;
    if (i >= Ncols * Ktot) return;
    int n = i / Ktot, k = i - n * Ktot;
    float v = (k < K0) ? root[(size_t)k * Ncols + n]
                       : W[(size_t)(k - K0) * Ncols + n];
    WT[(size_t)n * Ktot + k] = f2b(v);
}

// ---------------- per-(node,rel) mean gather into AG [node][rel*D + c] ----------------
template<int D>
__global__ __launch_bounds__(256) void agg_k(const short* __restrict__ X, int ldx,
                                             const int* __restrict__ off,
                                             const int* __restrict__ es,
                                             short* __restrict__ AG, int lda,
                                             int node0, int ncells) {
    constexpr int LPC = D / 4;                 // lanes per cell (32 or 64)
    int sub  = threadIdx.x / LPC;
    int lane = threadIdx.x % LPC;
    int ci = blockIdx.x * (256 / LPC) + sub;
    if (ci >= ncells) return;
    int node = ci / NREL, rel = ci - node * NREL;
    int gcell = (node0 + node) * NREL + rel;
    int beg = off[gcell], end = off[gcell + 1];
    int c0 = lane * 4;
    float s0 = 0.f, s1 = 0.f, s2 = 0.f, s3 = 0.f;
    int j = beg;
    for (; j + 1 < end; j += 2) {
        s16x4 v = *(const s16x4*)(X + (size_t)es[j] * ldx + c0);
        s16x4 w = *(const s16x4*)(X + (size_t)es[j + 1] * ldx + c0);
        s0 += b2f(v[0]) + b2f(w[0]);
        s1 += b2f(v[1]) + b2f(w[1]);
        s2 += b2f(v[2]) + b2f(w[2]);
        s3 += b2f(v[3]) + b2f(w[3]);
    }
    if (j < end) {
        s16x4 v = *(const s16x4*)(X + (size_t)es[j] * ldx + c0);
        s0 += b2f(v[0]); s1 += b2f(v[1]); s2 += b2f(v[2]); s3 += b2f(v[3]);
    }
    float inv = (end > beg) ? 1.f / (float)(end - beg) : 0.f;
    s16x4 o;
    o[0] = f2b(s0 * inv); o[1] = f2b(s1 * inv);
    o[2] = f2b(s2 * inv); o[3] = f2b(s3 * inv);
    *(s16x4*)(AG + (size_t)node * lda + rel * D + c0) = o;
}

// ---------------- bf16 MFMA GEMM, 3-buffer / 2-ahead pipeline ----------------
// C[M,Ncols] = [A0 | A1] @ BT^T (+bias,+relu).  k < Ksplit from A0, else A1.
// NBUF=3 LDS buffers, prefetch AHEAD=2 tiles: loads for tile k+2 issued during
// compute of tile k, counted s_waitcnt never drains below 2 tiles in flight
// (steady vmcnt = 2*LPS).  Raw s_barrier + sched_barrier(0) (rule #18).
// BN=128: 4 waves as 2x2 (64x64/wave), 4 loads/thread/stage, LDS 48KB (3 blk/CU).
// BN=64 : 4 waves as 4x1 (32x64/wave), 3 loads/thread/stage, LDS 36KB (4 blk/CU)
//         -> doubles grid for Ncols=128 outputs (conv3/enc3: 391 -> 782 blocks).
// XOR swizzle: slot(r,c) = r*4 + (c ^ (r&3) ^ ((r>>2)&1)); linear DMA dest,
// inverse permutation applied to the per-lane global source address.
#define ACH(R, q) ((((R) << 2) | ((q) ^ ((R) & 3) ^ (((R) >> 2) & 1))) * 8)
#define WAITV(N) asm volatile("s_waitcnt vmcnt(" #N ")" ::: "memory")

template<int BN>
__global__ __launch_bounds__(256) void gemm_bt_k(
    const short* __restrict__ A0, int ld0,
    const short* __restrict__ A1, int ld1, int Ksplit,
    const short* __restrict__ BT,
    int M, int K, int Ncols,
    const float* __restrict__ bias, int relu,
    short* __restrict__ Cb, int ldcb,
    float* __restrict__ Cf, int ldcf) {
    constexpr int NBUF = 3;
    constexpr int MT = (BN == 128) ? 4 : 2;            // M fragments per wave
    __shared__ __align__(16) short As[NBUF * 128 * 32];
    __shared__ __align__(16) short Bs[NBUF * BN * 32];
    const int tid = threadIdx.x;
    const int wave = tid >> 6, lane = tid & 63;
    const int l16 = lane & 15, quad = lane >> 4;
    const int bm = blockIdx.x * 128, bn = blockIdx.y * BN;
    const int wm = (BN == 128) ? (wave & 1) * 64 : wave * 32;
    const int wn = (BN == 128) ? (wave >> 1) * 64 : 0;

    // staging slots (linear DMA dest == tid order), pre-swizzled source coords
    const int s0 = tid, s1 = tid + 256;
    const int r0 = s0 >> 2, c0 = (s0 & 3) ^ (r0 & 3) ^ ((r0 >> 2) & 1);
    const int r1 = s1 >> 2, c1 = (s1 & 3) ^ (r1 & 3) ^ ((r1 >> 2) & 1);

    auto stage = [&](int buf, int k0) {
        const short* Ab; int lda; int kk;
        if (k0 < Ksplit) { Ab = A0; lda = ld0; kk = k0; }
        else             { Ab = A1; lda = ld1; kk = k0 - Ksplit; }
        short* at = As + buf * (128 * 32);
        short* bt = Bs + buf * (BN * 32);
        gload16(Ab + (size_t)(bm + r0) * lda + kk + c0 * 8, at + (wave * 64) * 8);
        gload16(Ab + (size_t)(bm + r1) * lda + kk + c1 * 8, at + (256 + wave * 64) * 8);
        gload16(BT + (size_t)(bn + r0) * K + k0 + c0 * 8, bt + (wave * 64) * 8);
        if (BN == 128)
            gload16(BT + (size_t)(bn + r1) * K + k0 + c1 * 8, bt + (256 + wave * 64) * 8);
    };

    f32x4 acc[MT][4];
    #pragma unroll
    for (int i = 0; i < MT; ++i)
        #pragma unroll
        for (int j = 0; j < 4; ++j)
            acc[i][j] = (f32x4)0.f;

    const int nk = K >> 5;
    stage(0, 0);
    if (nk > 1) stage(1, 32);
    for (int it = 0; it < nk; ++it) {
        const int cur = it % NBUF;
        if (it + 2 < nk) {
            stage((it + 2) % NBUF, (it + 2) << 5);   // keep 2 tiles in flight
            if (BN == 128) { WAITV(8); } else { WAITV(6); }
        } else if (it + 1 < nk) {
            if (BN == 128) { WAITV(4); } else { WAITV(3); }
        } else {
            WAITV(0);
        }
        __builtin_amdgcn_sched_barrier(0);
        __builtin_amdgcn_s_barrier();            // cur buffer complete on all waves
        __builtin_amdgcn_sched_barrier(0);
        const short* at = As + cur * (128 * 32);
        const short* bt = Bs + cur * (BN * 32);
        bf16x8 af[MT], bf[4];
        #pragma unroll
        for (int mt = 0; mt < MT; ++mt)
            af[mt] = *(const bf16x8*)&at[ACH(wm + mt * 16 + l16, quad)];
        #pragma unroll
        for (int nt = 0; nt < 4; ++nt)
            bf[nt] = *(const bf16x8*)&bt[ACH(wn + nt * 16 + l16, quad)];
        #pragma unroll
        for (int mt = 0; mt < MT; ++mt)
            #pragma unroll
            for (int nt = 0; nt < 4; ++nt)
                acc[mt][nt] = __builtin_amdgcn_mfma_f32_16x16x32_bf16(
                    af[mt], bf[nt], acc[mt][nt], 0, 0, 0);
        __builtin_amdgcn_sched_barrier(0);
        __builtin_amdgcn_s_barrier();            // all waves done reading cur
    }

    float bv[4];
    #pragma unroll
    for (int nt = 0; nt < 4; ++nt) bv[nt] = bias[bn + wn + nt * 16 + l16];

    #pragma unroll
    for (int mt = 0; mt < MT; ++mt) {
        int rb = bm + wm + mt * 16 + quad * 4;
        #pragma unroll
        for (int nt = 0; nt < 4; ++nt) {
            int gc = bn + wn + nt * 16 + l16;
            #pragma unroll
            for (int r = 0; r < 4; ++r) {
                int grow = rb + r;
                if (grow < M) {
                    float v = acc[mt][nt][r] + bv[nt];
                    if (relu) v = fmaxf(v, 0.f);
                    if (Cb) Cb[(size_t)grow * ldcb + gc] = f2b(v);
                    else    Cf[(size_t)grow * ldcf + gc] = v;
                }
            }
        }
    }
}

// ---------------- host ----------------
extern "C" void kernel_launch(void* const* d_in, const int* in_sizes, int n_in,
                              void* d_out, int out_size, void* d_ws, size_t ws_size,
                              hipStream_t stream) {
    const float* x      = (const float*)d_in[0];
    const int*   ei     = (const int*)d_in[1];
    const int*   srcv   = ei;
    const int*   dstv   = ei + EE;
    const int*   et     = (const int*)d_in[2];
    const float* enc_w0 = (const float*)d_in[3];
    const float* enc_b0 = (const float*)d_in[4];
    const float* enc_w1 = (const float*)d_in[5];
    const float* enc_b1 = (const float*)d_in[6];
    const float* enc_w2 = (const float*)d_in[7];
    const float* enc_b2 = (const float*)d_in[8];
    const float* W1     = (const float*)d_in[9];
    const float* root1  = (const float*)d_in[10];
    const float* b1     = (const float*)d_in[11];
    const float* W2     = (const float*)d_in[12];
    const float* root2  = (const float*)d_in[13];
    const float* b2     = (const float*)d_in[14];
    const float* W3     = (const float*)d_in[15];
    const float* root3  = (const float*)d_in[16];
    const float* b3     = (const float*)d_in[17];
    float* out = (float*)d_out;

    const int NPAD = 50048;                    // 391*128

    char* p = (char*)d_ws;
    auto alloc = [&](size_t bytes) -> char* {
        char* r = p; p += (bytes + 255) & ~(size_t)255; return r;
    };
    short* xb  = (short*)alloc((size_t)NPAD * INC * 2);
    short* g1  = (short*)alloc((size_t)NPAD * OUTC * 2);
    short* g2  = (short*)alloc((size_t)NPAD * OUTC * 2);
    short* WT1 = (short*)alloc((size_t)OUTC * 896 * 2);
    short* WT2 = (short*)alloc((size_t)OUTC * 1792 * 2);
    short* WT3 = (short*)alloc((size_t)HALF * 1792 * 2);
    short* ET0 = (short*)alloc((size_t)OUTC * INC * 2);
    short* ET1 = (short*)alloc((size_t)OUTC * OUTC * 2);
    short* ET2 = (short*)alloc((size_t)HALF * OUTC * 2);
    int* CNT  = (int*)alloc((size_t)NCELL * 4);
    int* OFF  = (int*)alloc((size_t)(NCELL + 1) * 4);
    int* CUR  = (int*)alloc((size_t)NCELL * 4);
    int* ES   = (int*)alloc((size_t)EE * 4);
    int* BSUM = (int*)alloc(1024 * 4);
    size_t fixed = (size_t)(p - (char*)d_ws);

    // agg buffer holds only the 6 relation blocks (self comes straight from A0)
    int chunk = 50000;
    if (fixed + (size_t)50048 * 1536 * 2 > ws_size) chunk = 25000;
    if (chunk == 25000 && fixed + (size_t)25088 * 1536 * 2 > ws_size) chunk = 12500;
    int crpad = ((chunk + 127) / 128) * 128;
    short* AG = (short*)alloc((size_t)crpad * 1536 * 2);

    // ---- CSR build (once; edge structure shared by all 3 layers)
    hipMemsetAsync(CNT, 0, (size_t)NCELL * 4, stream);
    count_k<<<EE / 256, 256, 0, stream>>>(dstv, et, CNT);
    int nbA = (NCELL + 511) / 512;
    scanA_k<<<nbA, 256, 0, stream>>>(CNT, OFF, BSUM, NCELL);
    scanB_k<<<1, 1024, 0, stream>>>(BSUM, nbA);
    scanC_k<<<(NCELL + 255) / 256, 256, 0, stream>>>(OFF, BSUM, NCELL);
    copyint_k<<<(NCELL + 255) / 256, 256, 0, stream>>>(OFF, CUR, NCELL);
    fill_k<<<EE / 256, 256, 0, stream>>>(srcv, dstv, et, CUR, ES);

    // ---- weight transposes + input cast
    cast_x_k<<<(NN * INC / 4 + 255) / 256, 256, 0, stream>>>(x, xb, NN * INC / 4);
    wtcat_k<<<(OUTC * 896 + 255) / 256, 256, 0, stream>>>(root1, W1, INC, 896, OUTC, WT1);
    wtcat_k<<<(OUTC * 1792 + 255) / 256, 256, 0, stream>>>(root2, W2, OUTC, 1792, OUTC, WT2);
    wtcat_k<<<(HALF * 1792 + 255) / 256, 256, 0, stream>>>(root3, W3, OUTC, 1792, HALF, WT3);
    wtcat_k<<<(OUTC * INC + 255) / 256, 256, 0, stream>>>(enc_w0, nullptr, INC, INC, OUTC, ET0);
    wtcat_k<<<(OUTC * OUTC + 255) / 256, 256, 0, stream>>>(enc_w1, nullptr, OUTC, OUTC, OUTC, ET1);
    wtcat_k<<<(HALF * OUTC + 255) / 256, 256, 0, stream>>>(enc_w2, nullptr, OUTC, OUTC, HALF, ET2);

    auto gemm = [&](const short* A0, int ld0, const short* A1, int ld1, int Ksplit,
                    const short* BT, int M, int K, int Ncols,
                    const float* bias, int relu, short* Cb, int ldcb, float* Cf, int ldcf) {
        if (Ncols >= 256) {
            dim3 grid((M + 127) / 128, Ncols / 128);
            gemm_bt_k<128><<<grid, 256, 0, stream>>>(A0, ld0, A1, ld1, Ksplit, BT,
                                                     M, K, Ncols, bias, relu, Cb, ldcb, Cf, ldcf);
        } else {
            dim3 grid((M + 127) / 128, Ncols / 64);
            gemm_bt_k<64><<<grid, 256, 0, stream>>>(A0, ld0, A1, ld1, Ksplit, BT,
                                                    M, K, Ncols, bias, relu, Cb, ldcb, Cf, ldcf);
        }
    };

    // ---- encoder
    gemm(xb, INC, nullptr, 0, INC, ET0, NN, INC, OUTC, enc_b0, 1, g1, OUTC, nullptr, 0);
    gemm(g1, OUTC, nullptr, 0, OUTC, ET1, NN, OUTC, OUTC, enc_b1, 1, g2, OUTC, nullptr, 0);
    gemm(g2, OUTC, nullptr, 0, OUTC, ET2, NN, OUTC, HALF, enc_b2, 0, nullptr, 0, out, OUTC);

    // ---- conv1: xb(128) -> g1
    for (int c0 = 0; c0 < NN; c0 += chunk) {
        int nc = chunk * NREL;
        agg_k<INC><<<(nc + 7) / 8, 256, 0, stream>>>(xb, INC, OFF, ES, AG, 768, c0, nc);
        gemm(xb + (size_t)c0 * INC, INC, AG, 768, INC, WT1, chunk, 896, OUTC,
             b1, 1, g1 + (size_t)c0 * OUTC, OUTC, nullptr, 0);
    }
    // ---- conv2: g1(256) -> g2
    for (int c0 = 0; c0 < NN; c0 += chunk) {
        int nc = chunk * NREL;
        agg_k<OUTC><<<(nc + 3) / 4, 256, 0, stream>>>(g1, OUTC, OFF, ES, AG, 1536, c0, nc);
        gemm(g1 + (size_t)c0 * OUTC, OUTC, AG, 1536, OUTC, WT2, chunk, 1792, OUTC,
             b2, 1, g2 + (size_t)c0 * OUTC, OUTC, nullptr, 0);
    }
    // ---- conv3: g2(256) -> out[:,128:]
    for (int c0 = 0; c0 < NN; c0 += chunk) {
        int nc = chunk * NREL;
        agg_k<OUTC><<<(nc + 3) / 4, 256, 0, stream>>>(g2, OUTC, OFF, ES, AG, 1536, c0, nc);
        gemm(g2 + (size_t)c0 * OUTC, OUTC, AG, 1536, OUTC, WT3, chunk, 1792, HALF,
             b3, 0, nullptr, 0, out + (size_t)c0 * OUTC + HALF, OUTC);
    }
}

// Round 4
// 733.172 us; speedup vs baseline: 1.0742x; 1.0742x over previous
//
#include <hip/hip_runtime.h>

#define NN   50000
#define EE   800000
#define INC  128
#define OUTC 256
#define HALF 128
#define NREL 6
#define NCELL (NN * NREL)   // 300000
#define NPAD 50048          // 391*128

typedef __attribute__((ext_vector_type(4))) short s16x4;
typedef __attribute__((ext_vector_type(8))) short bf16x8;
typedef __attribute__((ext_vector_type(4))) float f32x4;

__device__ __forceinline__ float b2f(short b) {
    unsigned u = ((unsigned)(unsigned short)b) << 16;
    return __uint_as_float(u);
}
__device__ __forceinline__ short f2b(float f) {
    unsigned u = __float_as_uint(f);
    unsigned r = (u + 0x7fffu + ((u >> 16) & 1u)) >> 16;   // RNE
    return (short)r;
}

__device__ __forceinline__ void gload16(const void* g, void* l) {
    __builtin_amdgcn_global_load_lds(
        (const __attribute__((address_space(1))) void*)g,
        (__attribute__((address_space(3))) void*)l, 16, 0, 0);
}

// ---------------- CSR build ----------------
__global__ __launch_bounds__(256) void count_k(const int* __restrict__ dst,
                                               const int* __restrict__ et,
                                               int* __restrict__ cnt) {
    int e = blockIdx.x * 256 + threadIdx.x;
    if (e < EE) atomicAdd(&cnt[dst[e] * NREL + et[e]], 1);
}

__global__ __launch_bounds__(256) void scanA_k(const int* __restrict__ cnt,
                                               int* __restrict__ off,
                                               int* __restrict__ bsum, int n) {
    __shared__ int sh[256];
    int t = threadIdx.x;
    int base = blockIdx.x * 512 + t * 2;
    int v0 = (base < n) ? cnt[base] : 0;
    int v1 = (base + 1 < n) ? cnt[base + 1] : 0;
    int s = v0 + v1;
    sh[t] = s; __syncthreads();
    for (int o = 1; o < 256; o <<= 1) {
        int u = (t >= o) ? sh[t - o] : 0;
        __syncthreads();
        sh[t] += u;
        __syncthreads();
    }
    int excl = sh[t] - s;
    if (base < n)     off[base]     = excl;
    if (base + 1 < n) off[base + 1] = excl + v0;
    if (t == 255) bsum[blockIdx.x] = sh[255];
}

__global__ __launch_bounds__(1024) void scanB_k(int* __restrict__ bsum, int nb) {
    __shared__ int sh[1024];
    int t = threadIdx.x;
    int s = (t < nb) ? bsum[t] : 0;
    sh[t] = s; __syncthreads();
    for (int o = 1; o < 1024; o <<= 1) {
        int u = (t >= o) ? sh[t - o] : 0;
        __syncthreads();
        sh[t] += u;
        __syncthreads();
    }
    if (t < nb) bsum[t] = sh[t] - s;
}

__global__ __launch_bounds__(256) void scanC_k(int* __restrict__ off,
                                               const int* __restrict__ bsum, int n) {
    int i = blockIdx.x * 256 + threadIdx.x;
    if (i < n) off[i] += bsum[i >> 9];
    if (i == 0) off[n] = EE;
}

__global__ __launch_bounds__(256) void copyint_k(const int* __restrict__ a,
                                                 int* __restrict__ b, int n) {
    int i = blockIdx.x * 256 + threadIdx.x;
    if (i < n) b[i] = a[i];
}

__global__ __launch_bounds__(256) void fill_k(const int* __restrict__ src,
                                              const int* __restrict__ dst,
                                              const int* __restrict__ et,
                                              int* __restrict__ cur,
                                              int* __restrict__ es) {
    int e = blockIdx.x * 256 + threadIdx.x;
    if (e < EE) {
        int key = dst[e] * NREL + et[e];
        int p = atomicAdd(&cur[key], 1);
        es[p] = src[e];
    }
}

// ---------------- casts ----------------
__global__ __launch_bounds__(256) void cast_x_k(const float* __restrict__ x,
                                                short* __restrict__ xb, int n4) {
    int i = blockIdx.x * 256 + threadIdx.x;
    if (i < n4) {
        float4 v = ((const float4*)x)[i];
        s16x4 o;
        o[0] = f2b(v.x); o[1] = f2b(v.y); o[2] = f2b(v.z); o[3] = f2b(v.w);
        ((s16x4*)xb)[i] = o;
    }
}

// BT[Ncols][K] = [root | W_0 .. W_5]^T (bf16).  root: [K][D], W: [NREL][K][D].
// Encoder matrices: W==null, Ncols==D.
__global__ __launch_bounds__(256) void wtcat2_k(const float* __restrict__ root,
                                                const float* __restrict__ W,
                                                int K, int D, int Ncols,
                                                short* __restrict__ BT) {
    int i = blockIdx.x * 256 + threadIdx.x;
    if (i >= Ncols * K) return;
    int n = i / K, k = i - n * K;
    float v;
    if (n < D) {
        v = root[(size_t)k * D + n];
    } else {
        int nn = n - D;
        int r = nn / D, c = nn - r * D;
        v = W[((size_t)r * K + k) * D + c];
    }
    BT[(size_t)n * K + k] = f2b(v);
}

// ---------------- bf16 MFMA GEMM ----------------
// C[M,Ncols] = A @ BT^T (+bias, +relu).  Single-buffer 2-barrier K-loop (the
// 3 pipeline variants measured identical; TLP from the wide grid hides latency).
// EPILOGUE: stage each 32x128 acc slab in LDS, re-read as 16 B/lane contiguous
// chunks, store with full-64B-line coverage -> TCC write-allocate fill
// eliminated (R1's wide-H GEMM paid ~154 MB of fills from 2-B scattered stores).
#define ACH(R, q) ((((R) << 2) | ((q) ^ ((R) & 3) ^ (((R) >> 2) & 1))) * 8)

__global__ __launch_bounds__(256) void gemm_bt_k(
    const short* __restrict__ A, int lda,
    const short* __restrict__ BT,
    int M, int K, int Ncols,
    const float* __restrict__ bias, int relu,
    short* __restrict__ Cb, int ldcb,
    float* __restrict__ Cf, int ldcf) {
    __shared__ __align__(16) char smem[16384];
    short* As = (short*)smem;                // [128*32] bf16
    short* Bs = As + 128 * 32;               // [128*32] bf16
    const int tid = threadIdx.x;
    const int wave = tid >> 6, lane = tid & 63;
    const int wm = (wave & 1) * 64, wn = (wave >> 1) * 64;
    const int l16 = lane & 15, quad = lane >> 4;
    const int bm = blockIdx.x * 128, bn = blockIdx.y * 128;

    // staging slots (linear DMA dest == tid order), pre-swizzled source coords
    const int s0 = tid, s1 = tid + 256;
    const int r0 = s0 >> 2, c0 = (s0 & 3) ^ (r0 & 3) ^ ((r0 >> 2) & 1);
    const int r1 = s1 >> 2, c1 = (s1 & 3) ^ (r1 & 3) ^ ((r1 >> 2) & 1);

    f32x4 acc[4][4];
    #pragma unroll
    for (int i = 0; i < 4; ++i)
        #pragma unroll
        for (int j = 0; j < 4; ++j)
            acc[i][j] = (f32x4)0.f;

    for (int k0 = 0; k0 < K; k0 += 32) {
        gload16(A + (size_t)(bm + r0) * lda + k0 + c0 * 8, As + (wave * 64) * 8);
        gload16(A + (size_t)(bm + r1) * lda + k0 + c1 * 8, As + (256 + wave * 64) * 8);
        gload16(BT + (size_t)(bn + r0) * K + k0 + c0 * 8, Bs + (wave * 64) * 8);
        gload16(BT + (size_t)(bn + r1) * K + k0 + c1 * 8, Bs + (256 + wave * 64) * 8);
        __syncthreads();
        bf16x8 af[4], bf[4];
        #pragma unroll
        for (int mt = 0; mt < 4; ++mt)
            af[mt] = *(const bf16x8*)&As[ACH(wm + mt * 16 + l16, quad)];
        #pragma unroll
        for (int nt = 0; nt < 4; ++nt)
            bf[nt] = *(const bf16x8*)&Bs[ACH(wn + nt * 16 + l16, quad)];
        #pragma unroll
        for (int mt = 0; mt < 4; ++mt)
            #pragma unroll
            for (int nt = 0; nt < 4; ++nt)
                acc[mt][nt] = __builtin_amdgcn_mfma_f32_16x16x32_bf16(
                    af[mt], bf[nt], acc[mt][nt], 0, 0, 0);
        __syncthreads();
    }

    float bv[4];
    #pragma unroll
    for (int nt = 0; nt < 4; ++nt)
        bv[nt] = bias ? bias[bn + wn + nt * 16 + l16] : 0.f;

    // slab row: sr = (wave&1)*16 + quad*4 + r  <->  grow = bm + (sr>>4)*64 + mt*16 + (sr&15)
    if (Cb) {
        short* Es = (short*)smem;            // [32][128] bf16 slab
        #pragma unroll
        for (int mt = 0; mt < 4; ++mt) {
            __syncthreads();                 // previous pass reads (or K-loop) done
            int srb = (wave & 1) * 16 + quad * 4;
            #pragma unroll
            for (int nt = 0; nt < 4; ++nt) {
                int sc = wn + nt * 16 + l16;
                #pragma unroll
                for (int r = 0; r < 4; ++r) {
                    float v = acc[mt][nt][r] + bv[nt];
                    if (relu) v = fmaxf(v, 0.f);
                    Es[(srb + r) * 128 + sc] = f2b(v);
                }
            }
            __syncthreads();
            #pragma unroll
            for (int h = 0; h < 2; ++h) {
                int c = tid + h * 256;       // chunk 0..511: 32 rows x 16 chunks
                int rr = c >> 4, cc = c & 15;
                int grow = bm + (rr >> 4) * 64 + mt * 16 + (rr & 15);
                if (grow < M)
                    *(bf16x8*)(Cb + (size_t)grow * ldcb + bn + cc * 8) =
                        *(const bf16x8*)&Es[rr * 128 + cc * 8];
            }
        }
    } else {
        float* Ef = (float*)smem;            // [32][128] f32 slab (16 KB)
        #pragma unroll
        for (int mt = 0; mt < 4; ++mt) {
            __syncthreads();
            int srb = (wave & 1) * 16 + quad * 4;
            #pragma unroll
            for (int nt = 0; nt < 4; ++nt) {
                int sc = wn + nt * 16 + l16;
                #pragma unroll
                for (int r = 0; r < 4; ++r) {
                    float v = acc[mt][nt][r] + bv[nt];
                    if (relu) v = fmaxf(v, 0.f);
                    Ef[(srb + r) * 128 + sc] = v;
                }
            }
            __syncthreads();
            #pragma unroll
            for (int h = 0; h < 4; ++h) {
                int c = tid + h * 256;       // chunk 0..1023: 32 rows x 32 chunks
                int rr = c >> 5, cc = c & 31;
                int grow = bm + (rr >> 4) * 64 + mt * 16 + (rr & 15);
                if (grow < M)
                    *(float4*)(Cf + (size_t)grow * ldcf + bn + cc * 4) =
                        *(const float4*)&Ef[rr * 128 + cc * 4];
            }
        }
    }
}

// ---------------- post-GEMM gather-aggregate ----------------
// out[i] = (accin? accin[i]:0) + (self0? H[i, 0:D]:0)
//        + sum_{r in [rfirst,rlast)} mean_{j in cell(i,r)} H[j, (colbase+r)*D : +D]
//        (+bias, +relu).  Writes bf16 (Ob) or f32 (Of).
template<int D>
__global__ __launch_bounds__(256) void gagg_k(
    const short* __restrict__ H, int ldh,
    int rfirst, int rlast, int colbase, int self0,
    const int* __restrict__ off, const int* __restrict__ es,
    const float* __restrict__ accin,
    const float* __restrict__ bias, int relu,
    short* __restrict__ Ob, float* __restrict__ Of, int ldo) {
    constexpr int LPN = D / 4;          // lanes per node (64 or 32)
    constexpr int NPB = 256 / LPN;      // nodes per block (4 or 8)
    int sub = threadIdx.x / LPN, lane = threadIdx.x % LPN;
    int node = blockIdx.x * NPB + sub;
    if (node >= NN) return;
    int c0 = lane * 4;

    float a0, a1, a2, a3;
    if (accin) {
        float4 t = *(const float4*)(accin + (size_t)node * D + c0);
        a0 = t.x; a1 = t.y; a2 = t.z; a3 = t.w;
    } else {
        a0 = a1 = a2 = a3 = 0.f;
    }
    if (self0) {
        s16x4 v = *(const s16x4*)(H + (size_t)node * ldh + c0);
        a0 += b2f(v[0]); a1 += b2f(v[1]); a2 += b2f(v[2]); a3 += b2f(v[3]);
    }
    int cell0 = node * NREL;
    for (int r = rfirst; r < rlast; ++r) {
        int beg = off[cell0 + r], end = off[cell0 + r + 1];
        if (end == beg) continue;
        int colo = (colbase + r) * D + c0;
        float s0 = 0.f, s1 = 0.f, s2 = 0.f, s3 = 0.f;
        int j = beg;
        for (; j + 1 < end; j += 2) {
            s16x4 v = *(const s16x4*)(H + (size_t)es[j] * ldh + colo);
            s16x4 w = *(const s16x4*)(H + (size_t)es[j + 1] * ldh + colo);
            s0 += b2f(v[0]) + b2f(w[0]);
            s1 += b2f(v[1]) + b2f(w[1]);
            s2 += b2f(v[2]) + b2f(w[2]);
            s3 += b2f(v[3]) + b2f(w[3]);
        }
        if (j < end) {
            s16x4 v = *(const s16x4*)(H + (size_t)es[j] * ldh + colo);
            s0 += b2f(v[0]); s1 += b2f(v[1]); s2 += b2f(v[2]); s3 += b2f(v[3]);
        }
        float inv = 1.f / (float)(end - beg);
        a0 += s0 * inv; a1 += s1 * inv; a2 += s2 * inv; a3 += s3 * inv;
    }
    if (bias) {
        float4 bv = *(const float4*)(bias + c0);
        a0 += bv.x; a1 += bv.y; a2 += bv.z; a3 += bv.w;
    }
    if (relu) {
        a0 = fmaxf(a0, 0.f); a1 = fmaxf(a1, 0.f);
        a2 = fmaxf(a2, 0.f); a3 = fmaxf(a3, 0.f);
    }
    if (Ob) {
        s16x4 o;
        o[0] = f2b(a0); o[1] = f2b(a1); o[2] = f2b(a2); o[3] = f2b(a3);
        *(s16x4*)(Ob + (size_t)node * ldo + c0) = o;
    } else {
        float4 o; o.x = a0; o.y = a1; o.z = a2; o.w = a3;
        *(float4*)(Of + (size_t)node * ldo + c0) = o;
    }
}

// ---------------- host ----------------
extern "C" void kernel_launch(void* const* d_in, const int* in_sizes, int n_in,
                              void* d_out, int out_size, void* d_ws, size_t ws_size,
                              hipStream_t stream) {
    const float* x      = (const float*)d_in[0];
    const int*   ei     = (const int*)d_in[1];
    const int*   srcv   = ei;
    const int*   dstv   = ei + EE;
    const int*   et     = (const int*)d_in[2];
    const float* enc_w0 = (const float*)d_in[3];
    const float* enc_b0 = (const float*)d_in[4];
    const float* enc_w1 = (const float*)d_in[5];
    const float* enc_b1 = (const float*)d_in[6];
    const float* enc_w2 = (const float*)d_in[7];
    const float* enc_b2 = (const float*)d_in[8];
    const float* W1     = (const float*)d_in[9];
    const float* root1  = (const float*)d_in[10];
    const float* b1     = (const float*)d_in[11];
    const float* W2     = (const float*)d_in[12];
    const float* root2  = (const float*)d_in[13];
    const float* b2     = (const float*)d_in[14];
    const float* W3     = (const float*)d_in[15];
    const float* root3  = (const float*)d_in[16];
    const float* b3     = (const float*)d_in[17];
    float* out = (float*)d_out;

    char* p = (char*)d_ws;
    auto alloc = [&](size_t bytes) -> char* {
        char* r = p; p += (bytes + 255) & ~(size_t)255; return r;
    };
    short* xb  = (short*)alloc((size_t)NPAD * INC * 2);
    short* g1  = (short*)alloc((size_t)NPAD * OUTC * 2);
    short* g2  = (short*)alloc((size_t)NPAD * OUTC * 2);
    short* BT1 = (short*)alloc((size_t)1792 * INC * 2);    // [root1|W1_0..5]^T
    short* BT2 = (short*)alloc((size_t)1792 * OUTC * 2);   // [root2|W2_0..5]^T
    short* BT3 = (short*)alloc((size_t)896 * OUTC * 2);    // [root3|W3_0..5]^T
    short* ET0 = (short*)alloc((size_t)OUTC * INC * 2);
    short* ET1 = (short*)alloc((size_t)OUTC * OUTC * 2);
    short* ET2 = (short*)alloc((size_t)HALF * OUTC * 2);
    int* CNT  = (int*)alloc((size_t)NCELL * 4);
    int* OFF  = (int*)alloc((size_t)(NCELL + 1) * 4);
    int* CUR  = (int*)alloc((size_t)NCELL * 4);
    int* ES   = (int*)alloc((size_t)EE * 4);
    int* BSUM = (int*)alloc(1024 * 4);
    size_t fixed = (size_t)(p - (char*)d_ws);

    // Tier 1: full H (all 7 column blocks, 179.4 MB).
    // Tier 2: relation-split {root,0,1,2}/{3,4,5} + f32 ACC.
    bool fullH = fixed + (size_t)NPAD * 1792 * 2 <= ws_size;
    short* H = (short*)alloc(fullH ? (size_t)NPAD * 1792 * 2
                                   : (size_t)NPAD * 1024 * 2);
    float* ACC = fullH ? nullptr : (float*)alloc((size_t)NPAD * OUTC * 4);

    // ---- CSR build (once; edge structure shared by all 3 layers)
    hipMemsetAsync(CNT, 0, (size_t)NCELL * 4, stream);
    count_k<<<EE / 256, 256, 0, stream>>>(dstv, et, CNT);
    int nbA = (NCELL + 511) / 512;
    scanA_k<<<nbA, 256, 0, stream>>>(CNT, OFF, BSUM, NCELL);
    scanB_k<<<1, 1024, 0, stream>>>(BSUM, nbA);
    scanC_k<<<(NCELL + 255) / 256, 256, 0, stream>>>(OFF, BSUM, NCELL);
    copyint_k<<<(NCELL + 255) / 256, 256, 0, stream>>>(OFF, CUR, NCELL);
    fill_k<<<EE / 256, 256, 0, stream>>>(srcv, dstv, et, CUR, ES);

    // ---- weight transposes + input cast
    cast_x_k<<<(NN * INC / 4 + 255) / 256, 256, 0, stream>>>(x, xb, NN * INC / 4);
    auto wt = [&](const float* root, const float* W, int K, int D, int Ncols, short* BT) {
        wtcat2_k<<<(Ncols * K + 255) / 256, 256, 0, stream>>>(root, W, K, D, Ncols, BT);
    };
    wt(root1, W1, INC, OUTC, 1792, BT1);
    wt(root2, W2, OUTC, OUTC, 1792, BT2);
    wt(root3, W3, OUTC, HALF, 896, BT3);
    wt(enc_w0, nullptr, INC, OUTC, OUTC, ET0);
    wt(enc_w1, nullptr, OUTC, OUTC, OUTC, ET1);
    wt(enc_w2, nullptr, OUTC, HALF, HALF, ET2);

    auto gemm = [&](const short* A, int lda, const short* BT, int M, int K, int Ncols,
                    const float* bias, int relu, short* Cb, int ldcb, float* Cf, int ldcf) {
        dim3 grid((M + 127) / 128, Ncols / 128);
        gemm_bt_k<<<grid, 256, 0, stream>>>(A, lda, BT, M, K, Ncols,
                                            bias, relu, Cb, ldcb, Cf, ldcf);
    };

    // ---- encoder
    gemm(xb, INC, ET0, NN, INC, OUTC, enc_b0, 1, g1, OUTC, nullptr, 0);
    gemm(g1, OUTC, ET1, NN, OUTC, OUTC, enc_b1, 1, g2, OUTC, nullptr, 0);
    gemm(g2, OUTC, ET2, NN, OUTC, HALF, enc_b2, 0, nullptr, 0, out, OUTC);

    // ---- conv layers: transform-then-aggregate
    // H = A @ [root | W_0..W_5]  (one wide, well-shaped GEMM), then gather-mean.
    auto conv = [&](const short* A, int K, int D, const short* BT,
                    const float* bias, int relu, short* Ob, float* Of) {
        int NPB = 256 / (D / 4);
        int gg = (NN + NPB - 1) / NPB;
        if (fullH) {
            gemm(A, K, BT, NN, K, 7 * D, nullptr, 0, H, 7 * D, nullptr, 0);
            if (D == 256)
                gagg_k<256><<<gg, 256, 0, stream>>>(H, 7 * D, 0, NREL, 1, 1,
                    OFF, ES, nullptr, bias, relu, Ob, Of, OUTC);
            else
                gagg_k<128><<<gg, 256, 0, stream>>>(H, 7 * D, 0, NREL, 1, 1,
                    OFF, ES, nullptr, bias, relu, Ob, Of, OUTC);
        } else {
            // pass a: [root | W_0..W_2] -> f32 ACC
            gemm(A, K, BT, NN, K, 4 * D, nullptr, 0, H, 4 * D, nullptr, 0);
            if (D == 256)
                gagg_k<256><<<gg, 256, 0, stream>>>(H, 4 * D, 0, 3, 1, 1,
                    OFF, ES, nullptr, nullptr, 0, nullptr, ACC, D);
            else
                gagg_k<128><<<gg, 256, 0, stream>>>(H, 4 * D, 0, 3, 1, 1,
                    OFF, ES, nullptr, nullptr, 0, nullptr, ACC, D);
            // pass b: [W_3..W_5] + ACC -> final
            gemm(A, K, BT + (size_t)4 * D * K, NN, K, 3 * D, nullptr, 0, H, 3 * D, nullptr, 0);
            if (D == 256)
                gagg_k<256><<<gg, 256, 0, stream>>>(H, 3 * D, 3, NREL, -3, 0,
                    OFF, ES, ACC, bias, relu, Ob, Of, OUTC);
            else
                gagg_k<128><<<gg, 256, 0, stream>>>(H, 3 * D, 3, NREL, -3, 0,
                    OFF, ES, ACC, bias, relu, Ob, Of, OUTC);
        }
    };

    conv(xb, INC,  OUTC, BT1, b1, 1, g1, nullptr);        // conv1: K=128, N=1792
    conv(g1, OUTC, OUTC, BT2, b2, 1, g2, nullptr);        // conv2: K=256, N=1792
    conv(g2, OUTC, HALF, BT3, b3, 0, nullptr, out + HALF);// conv3: K=256, N=896
}